// Round 2
// baseline (190.160 us; speedup 1.0000x reference)
//
#include <hip/hip_runtime.h>
#include <math.h>

#define NTH 256
#define TB 8

static constexpr float HLP = 0.9189385332046727f; // 0.5*log(2*pi)

// ws layout (floats):
// [0, 130560)            normalized weights, layers concat (layer l: R=128>>l regions x 64 x 8)
// [130560, 132608)       leafA = exp(-log_sigma)       [256][8]
// [132608, 134656)       leafB = -log_sigma - HLP      [256][8]
// [134656, 134664)       srw   = softmax(root_w)       [8]
// [135168, 2232320)      xT    = x transposed [256][8192]
// [2232320, 3411968)     inter = layer-3 output [16 subtrees][9][8192]
static constexpr int NW   = 130560;
static constexpr int AOFF = NW;
static constexpr int BOFF = NW + 2048;
static constexpr int ROFF = NW + 4096;
static constexpr int XT_OFF  = 135168;
static constexpr int INT_OFF = XT_OFF + 256 * 8192;        // 2232320
static constexpr size_t WS_NEED_B = (size_t)(INT_OFF + 16 * 9 * 8192) * 4;

// weight base (in floats) for the layer that PRODUCES layer-L regions (L=0..7)
__device__ __forceinline__ int layer_base(int L) {
  return (256 - (256 >> L)) << 9;   // (256 - 256/2^L) * 512
}

// ---------------- prep: normalize weights, leaf constants, root softmax ----------------
__global__ __launch_bounds__(256) void spn_prep(
    const float* __restrict__ ls,
    const float* __restrict__ w0, const float* __restrict__ w1,
    const float* __restrict__ w2, const float* __restrict__ w3,
    const float* __restrict__ w4, const float* __restrict__ w5,
    const float* __restrict__ w6, const float* __restrict__ w7,
    const float* __restrict__ root_w,
    float* __restrict__ ws)
{
  const int job = blockIdx.x * blockDim.x + threadIdx.x;
  if (job < 2040) {
    const float* wl[8] = {w0, w1, w2, w3, w4, w5, w6, w7};
    int j = job, l = 0, base = 0, R = 128;
    while (j >= R * 8) { j -= R * 8; base += R * 512; R >>= 1; ++l; }
    const int r = j >> 3, k = j & 7;
    const float* src = wl[l] + r * 512 + k;
    float v[64];
    float m = -3.0e38f;
    #pragma unroll
    for (int c = 0; c < 64; ++c) { v[c] = src[c * 8]; m = fmaxf(m, v[c]); }
    float ssum = 0.f;
    #pragma unroll
    for (int c = 0; c < 64; ++c) { v[c] = __expf(v[c] - m); ssum += v[c]; }
    const float inv = 1.0f / ssum;
    float* dst = ws + base + r * 512 + k;
    #pragma unroll
    for (int c = 0; c < 64; ++c) dst[c * 8] = v[c] * inv;
  } else if (job < 2040 + 2048) {
    const int i = job - 2040;
    const float l = ls[i];
    ws[AOFF + i] = __expf(-l);
    ws[BOFF + i] = -l - HLP;
  } else if (job == 2040 + 2048) {
    float m = -3.0e38f;
    for (int k = 0; k < 8; ++k) m = fmaxf(m, root_w[k]);
    float e[8]; float ssum = 0.f;
    for (int k = 0; k < 8; ++k) { e[k] = __expf(root_w[k] - m); ssum += e[k]; }
    const float inv = 1.0f / ssum;
    for (int k = 0; k < 8; ++k) ws[ROFF + k] = e[k] * inv;
  }
}

// ---------------- x transpose: [8192][256] -> [256][8192] ----------------
__global__ __launch_bounds__(256) void spn_xpose(const float* __restrict__ x,
                                                 float* __restrict__ ws)
{
  __shared__ float t[32][33];
  float* xT = ws + XT_OFF;
  const int bx = blockIdx.x * 32;   // batch base
  const int fx = blockIdx.y * 32;   // feature base
  const int tx = threadIdx.x & 31, ty = threadIdx.x >> 5;  // 32 x 8
  #pragma unroll
  for (int j = 0; j < 4; ++j)
    t[ty + 8 * j][tx] = x[(size_t)(bx + ty + 8 * j) * 256 + fx + tx];
  __syncthreads();
  #pragma unroll
  for (int j = 0; j < 4; ++j)
    xT[(size_t)(fx + ty + 8 * j) * 8192 + bx + tx] = t[tx][ty + 8 * j];
}

// ---------------- shared math helpers ----------------
__device__ __forceinline__ void mac64(const float* __restrict__ Wr,
                                      const float* na, const float* nb,
                                      float* s) {
  #pragma unroll
  for (int k = 0; k < 8; ++k) s[k] = 0.f;
  #pragma unroll
  for (int i = 0; i < 8; ++i) {
    const float ai = na[i];
    #pragma unroll
    for (int j = 0; j < 8; ++j) {
      const float e = ai * nb[j];
      const float4 wA = *reinterpret_cast<const float4*>(Wr + (i * 8 + j) * 8);
      const float4 wB = *reinterpret_cast<const float4*>(Wr + (i * 8 + j) * 8 + 4);
      s[0] = fmaf(e, wA.x, s[0]); s[1] = fmaf(e, wA.y, s[1]);
      s[2] = fmaf(e, wA.z, s[2]); s[3] = fmaf(e, wA.w, s[3]);
      s[4] = fmaf(e, wB.x, s[4]); s[5] = fmaf(e, wB.y, s[5]);
      s[6] = fmaf(e, wB.z, s[6]); s[7] = fmaf(e, wB.w, s[7]);
    }
  }
}

__device__ __forceinline__ float max8(const float* s) {
  float m = s[0];
  #pragma unroll
  for (int k = 1; k < 8; ++k) m = fmaxf(m, s[k]);
  return m;
}

// combine: out_n = normalize(e(na) x e(nb) . W), Mio += log(smax)
__device__ __forceinline__ void combine(const float* __restrict__ W,
                                        const float* na, const float* nb,
                                        float* outn, float* Mio) {
  float s[8];
  mac64(W, na, nb, s);
  const float smax = max8(s);
  const float inv = 1.0f / smax;
  #pragma unroll
  for (int k = 0; k < 8; ++k) outn[k] = s[k] * inv;
  *Mio += __logf(smax);
}

__device__ __forceinline__ void leaf_eval(float xv,
                                          const float* __restrict__ mu8,
                                          const float* __restrict__ A8,
                                          const float* __restrict__ B8,
                                          float* n, float* M) {
  float h[8];
  float m = -3.0e38f;
  #pragma unroll
  for (int k = 0; k < 8; ++k) {
    const float z = (xv - mu8[k]) * A8[k];
    h[k] = fmaf(-0.5f * z, z, B8[k]);
    m = fmaxf(m, h[k]);
  }
  #pragma unroll
  for (int k = 0; k < 8; ++k) n[k] = __expf(h[k] - m);
  *M = m;
}

// ---------------- kernel A: layers 0..3 per subtree (DFS, lane = batch) ----------------
// grid: 512 blocks x 256 thr = 2048 waves; wave = (batch chunk, subtree)
__global__ __launch_bounds__(NTH) void spn_treeA(
    const float* __restrict__ mu,
    float* __restrict__ ws)
{
  __shared__ float stk[3 * 9 * NTH];   // [lvl][v][tid]

  const int lane = threadIdx.x & 63;
  const int wid  = __builtin_amdgcn_readfirstlane(threadIdx.x >> 6);
  const int gw   = blockIdx.x * (NTH / 64) + wid;
  const int s    = gw & 15;            // subtree (uniform)
  const int b    = (gw >> 4) * 64 + lane;

  const float* xT    = ws + XT_OFF;
  const float* leafA = ws + AOFF;
  const float* leafB = ws + BOFF;
  float*       inter = ws + INT_OFF;

  for (int p = 0; p < 8; ++p) {        // leaf-pair within subtree (uniform)
    const int P = s * 8 + p;           // global layer-0 region
    float na[8], nb[8], Ma, Mb;
    const int f0 = 2 * P;
    leaf_eval(xT[(size_t)f0 * 8192 + b],       mu + f0 * 8,     leafA + f0 * 8,     leafB + f0 * 8,     na, &Ma);
    leaf_eval(xT[(size_t)(f0 + 1) * 8192 + b], mu + f0 * 8 + 8, leafA + f0 * 8 + 8, leafB + f0 * 8 + 8, nb, &Mb);

    float cur[8];
    float curM = Ma + Mb;
    combine(ws + P * 512, na, nb, cur, &curM);   // layer-0 weights at base 0

    // merge up the binary-counter stack
    int idx = p, lvl = 0;
    while (idx & 1) {
      float sn[8];
      #pragma unroll
      for (int v = 0; v < 8; ++v) sn[v] = stk[(lvl * 9 + v) * NTH + threadIdx.x];
      float nM = stk[(lvl * 9 + 8) * NTH + threadIdx.x] + curM;
      float nxt[8];
      combine(ws + layer_base(lvl + 1) + (P >> (lvl + 1)) * 512, sn, cur, nxt, &nM);
      #pragma unroll
      for (int v = 0; v < 8; ++v) cur[v] = nxt[v];
      curM = nM;
      idx >>= 1; ++lvl;
    }

    if (p == 7) {
      #pragma unroll
      for (int v = 0; v < 8; ++v) inter[(size_t)(s * 9 + v) * 8192 + b] = cur[v];
      inter[(size_t)(s * 9 + 8) * 8192 + b] = curM;
    } else {
      #pragma unroll
      for (int v = 0; v < 8; ++v) stk[(lvl * 9 + v) * NTH + threadIdx.x] = cur[v];
      stk[(lvl * 9 + 8) * NTH + threadIdx.x] = curM;
    }
  }
}

// ---------------- kernel B: layers 4..7 + root (DFS over 16 stored regions) ----------------
// grid: 32 blocks x 256 thr = 128 waves; lane = batch
__global__ __launch_bounds__(NTH) void spn_treeB(
    float* __restrict__ ws,
    float* __restrict__ out)
{
  __shared__ float stk[4 * 9 * NTH];

  const int lane = threadIdx.x & 63;
  const int wid  = __builtin_amdgcn_readfirstlane(threadIdx.x >> 6);
  const int b    = (blockIdx.x * (NTH / 64) + wid) * 64 + lane;

  const float* inter = ws + INT_OFF;
  const float* srw   = ws + ROFF;

  for (int s = 0; s < 16; ++s) {
    float cur[8];
    #pragma unroll
    for (int v = 0; v < 8; ++v) cur[v] = inter[(size_t)(s * 9 + v) * 8192 + b];
    float curM = inter[(size_t)(s * 9 + 8) * 8192 + b];

    int idx = s, lvl = 0;
    while (idx & 1) {
      float sn[8];
      #pragma unroll
      for (int v = 0; v < 8; ++v) sn[v] = stk[(lvl * 9 + v) * NTH + threadIdx.x];
      float nM = stk[(lvl * 9 + 8) * NTH + threadIdx.x] + curM;
      float nxt[8];
      // merging two layer-(3+lvl) regions -> layer-(4+lvl) region (s >> (lvl+1))
      combine(ws + layer_base(4 + lvl) + (s >> (lvl + 1)) * 512, sn, cur, nxt, &nM);
      #pragma unroll
      for (int v = 0; v < 8; ++v) cur[v] = nxt[v];
      curM = nM;
      idx >>= 1; ++lvl;
    }

    if (s == 15) {
      float acc = 0.f;
      #pragma unroll
      for (int k = 0; k < 8; ++k) acc = fmaf(cur[k], srw[k], acc);
      out[b] = curM + __logf(acc);
    } else {
      #pragma unroll
      for (int v = 0; v < 8; ++v) stk[(lvl * 9 + v) * NTH + threadIdx.x] = cur[v];
      stk[(lvl * 9 + 8) * NTH + threadIdx.x] = curM;
    }
  }
}

// ================= fallback (round-1 kernel) for small ws =================
static constexpr int PLA = 128 * 9 + 5;
static constexpr int PLB = 64 * 9 + 5;
static constexpr int NAO = 0;
static constexpr int NBO = TB * PLA;
static constexpr int MAO = NBO + TB * PLB;
static constexpr int MBO = MAO + TB * 128;
static constexpr int SMEM_F = MBO + TB * 64;

__global__ __launch_bounds__(NTH, 2) void spn_main_fb(
    const float* __restrict__ x,
    const float* __restrict__ mu,
    const float* __restrict__ ws,
    float* __restrict__ out)
{
  const float* leafA = ws + AOFF;
  const float* leafB = ws + BOFF;
  const float* srw   = ws + ROFF;

  __shared__ float smem[SMEM_F];

  const int tid = threadIdx.x;
  const int bB = blockIdx.x * TB;

  {
    const float* W0 = ws;
    for (int it = tid; it < TB * 128; it += NTH) {
      const int bb = it & (TB - 1), r = it >> 3;
      float na[8], nb[8], Ma, Mb;
      const int f0 = 2 * r;
      const float xv0 = x[(bB + bb) * 256 + f0];
      const float xv1 = x[(bB + bb) * 256 + f0 + 1];
      leaf_eval(xv0, mu + f0 * 8, leafA + f0 * 8, leafB + f0 * 8, na, &Ma);
      leaf_eval(xv1, mu + f0 * 8 + 8, leafA + f0 * 8 + 8, leafB + f0 * 8 + 8, nb, &Mb);
      float s[8];
      mac64(W0 + r * 512, na, nb, s);
      const float smax = max8(s);
      const float inv = 1.0f / smax;
      const int ob = NAO + bb * PLA + r * 9;
      #pragma unroll
      for (int k = 0; k < 8; ++k) smem[ob + k] = s[k] * inv;
      smem[MAO + bb * 128 + r] = Ma + Mb + __logf(smax);
    }
  }
  __syncthreads();

  int pinO = NAO, poutO = NBO;
  int MinO = MAO, MoutO = MBO;
  int PLIN = PLA, PLOUT = PLB;
  int Rin = 128;
  const float* Wl = ws + 128 * 512;
  for (int l = 1; l < 7; ++l) {
    const int Rout = Rin >> 1;
    for (int it = tid; it < TB * Rout; it += NTH) {
      const int bb = it & (TB - 1), r = it >> 3;
      float na[8], nb[8];
      const int ia = pinO + bb * PLIN + (2 * r) * 9;
      #pragma unroll
      for (int i = 0; i < 8; ++i) { na[i] = smem[ia + i]; nb[i] = smem[ia + 9 + i]; }
      float s[8];
      mac64(Wl + r * 512, na, nb, s);
      const float smax = max8(s);
      const float inv = 1.0f / smax;
      const int ob = poutO + bb * PLOUT + r * 9;
      #pragma unroll
      for (int k = 0; k < 8; ++k) smem[ob + k] = s[k] * inv;
      smem[MoutO + bb * Rout + r] =
          smem[MinO + bb * Rin + 2 * r] + smem[MinO + bb * Rin + 2 * r + 1] + __logf(smax);
    }
    __syncthreads();
    int t;
    t = pinO; pinO = poutO; poutO = t;
    t = MinO; MinO = MoutO; MoutO = t;
    t = PLIN; PLIN = PLOUT; PLOUT = t;
    Rin = Rout;
    Wl += Rout * 512;
  }

  for (int it = tid; it < TB; it += NTH) {
    const int bb = it;
    float na[8], nb[8];
    const int ia = pinO + bb * PLIN;
    #pragma unroll
    for (int i = 0; i < 8; ++i) { na[i] = smem[ia + i]; nb[i] = smem[ia + 9 + i]; }
    float s[8];
    mac64(Wl, na, nb, s);
    float acc = 0.f;
    #pragma unroll
    for (int k = 0; k < 8; ++k) acc = fmaf(s[k], srw[k], acc);
    out[bB + bb] = smem[MinO + bb * 2] + smem[MinO + bb * 2 + 1] + __logf(acc);
  }
}

extern "C" void kernel_launch(void* const* d_in, const int* in_sizes, int n_in,
                              void* d_out, int out_size, void* d_ws, size_t ws_size,
                              hipStream_t stream) {
  const float* x      = (const float*)d_in[0];
  const float* mu     = (const float*)d_in[1];
  const float* ls     = (const float*)d_in[2];
  const float* w0     = (const float*)d_in[3];
  const float* w1     = (const float*)d_in[4];
  const float* w2     = (const float*)d_in[5];
  const float* w3     = (const float*)d_in[6];
  const float* w4     = (const float*)d_in[7];
  const float* w5     = (const float*)d_in[8];
  const float* w6     = (const float*)d_in[9];
  const float* w7     = (const float*)d_in[10];
  const float* root_w = (const float*)d_in[11];
  float* ws  = (float*)d_ws;
  float* out = (float*)d_out;

  spn_prep<<<16, 256, 0, stream>>>(ls, w0, w1, w2, w3, w4, w5, w6, w7, root_w, ws);

  if (ws_size >= WS_NEED_B) {
    spn_xpose<<<dim3(256, 8), 256, 0, stream>>>(x, ws);
    spn_treeA<<<512, NTH, 0, stream>>>(mu, ws);
    spn_treeB<<<32, NTH, 0, stream>>>(ws, out);
  } else {
    spn_main_fb<<<8192 / TB, NTH, 0, stream>>>(x, mu, ws, out);
  }
}